// Round 2
// baseline (169.631 us; speedup 1.0000x reference)
//
#include <hip/hip_runtime.h>
#include <hip/hip_bf16.h>

#define B_CLOUDS 16384
#define NPAIR 136
#define NOUT 17408   // 136 pairs * 128 features = 68*256

using frag8 = __attribute__((ext_vector_type(8))) short;
using f32x4 = __attribute__((ext_vector_type(4))) float;
using i32x4 = __attribute__((ext_vector_type(4))) int;

// Pack two f32 -> bf16x2 by truncation with ONE v_perm_b32.
// result low short = lo's top 16 bits, high short = hi's top 16 bits.
__device__ inline int pack_bf16(float lo, float hi){
  unsigned a, b;
  __builtin_memcpy(&a, &hi, 4);
  __builtin_memcpy(&b, &lo, 4);
  return (int)__builtin_amdgcn_perm(a, b, 0x07060302u);
}

// ---------------- gene: per-cloud 16x16 Gram via MFMA, K=512 ----------------
__global__ __launch_bounds__(256) void gene_kernel(const float* __restrict__ X,
                                                   const float* __restrict__ Y,
                                                   float* __restrict__ gene_part){
  const int wave = threadIdx.x >> 6;
  const int lane = threadIdx.x & 63;
  const int b = blockIdx.x * 4 + wave;          // grid=4096 -> one cloud per wave
  const int r = lane & 15;                      // row of Z (0-7 = X, 8-15 = Y)
  const int g = lane >> 4;                      // k-group
  const float* base = (r < 8) ? (X + (size_t)b*4096 + (size_t)r*512)
                              : (Y + (size_t)b*4096 + (size_t)(r-8)*512);
  const float* p = base + g*8;
  f32x4 acc = {0.f,0.f,0.f,0.f};
#pragma unroll
  for (int kk = 0; kk < 16; ++kk){
    const float4* q4 = reinterpret_cast<const float4*>(p + kk*32);
    float4 v0 = q4[0];
    float4 v1 = q4[1];
    i32x4 fi;
    fi[0] = pack_bf16(v0.x, v0.y);
    fi[1] = pack_bf16(v0.z, v0.w);
    fi[2] = pack_bf16(v1.x, v1.y);
    fi[3] = pack_bf16(v1.z, v1.w);
    frag8 fr = __builtin_bit_cast(frag8, fi);
    // A-frag and B-frag layouts coincide for Z*Z^T -> same registers both operands
    acc = __builtin_amdgcn_mfma_f32_16x16x32_bf16(fr, fr, acc, 0, 0, 0);
  }
  // C/D layout: col = lane&15, row = (lane>>4)*4 + q   (m89-verified)
  __shared__ float diag[4][16];
  const int col = r;
  const int row0 = g*4;
  const int qd = col - row0;
  if (qd >= 0 && qd < 4) diag[wave][col] = acc[qd];
  __syncthreads();
  float s = 0.f;
#pragma unroll
  for (int q = 0; q < 4; ++q){
    int row = row0 + q;
    float sqd = diag[wave][row] + diag[wave][col] - 2.f*acc[q];
    float dist = sqrtf(fmaxf(sqd, 0.f));
    s += (((row < 8) == (col < 8)) ? -dist : dist);
  }
  s *= (1.f/128.f);                             // per-cloud signed mean
#pragma unroll
  for (int off = 32; off > 0; off >>= 1) s += __shfl_xor(s, off);
  __shared__ float wsum[4];
  if (lane == 0) wsum[wave] = s;
  __syncthreads();
  if (threadIdx.x == 0) gene_part[blockIdx.x] = (wsum[0]+wsum[1])+(wsum[2]+wsum[3]);
}

// ---------------- cell: per-feature 16x16 Gram, K=16384, fp32 ----------------
struct PairTab { int pi[NPAIR]; int pj[NPAIR]; };
constexpr PairTab make_pairs(){
  PairTab t{}; int u = 0;
  for (int i = 0; i < 16; ++i) for (int j = i; j < 16; ++j){ t.pi[u]=i; t.pj[u]=j; ++u; }
  return t;
}
constexpr PairTab PT = make_pairs();

template<int H>
__device__ inline void cell_body(const float* __restrict__ X, const float* __restrict__ Y,
                                 float* __restrict__ partials, int f, int t, int p, int P){
  float acc[68];
#pragma unroll
  for (int u = 0; u < 68; ++u) acc[u] = 0.f;
  for (int b = p; b < B_CLOUDS; b += P){
    const float* xb = X + (size_t)b*4096 + 384 + f;
    const float* yb = Y + (size_t)b*4096 + 384 + f;
    float z[16];
#pragma unroll
    for (int i = 0; i < 8; ++i) z[i]   = xb[(size_t)i*512];
#pragma unroll
    for (int i = 0; i < 8; ++i) z[8+i] = yb[(size_t)i*512];
#pragma unroll
    for (int u = 0; u < 68; ++u)   // compile-time indices (template H) -> all regs
      acc[u] = fmaf(z[PT.pi[H*68+u]], z[PT.pj[H*68+u]], acc[u]);
  }
#pragma unroll
  for (int u = 0; u < 68; ++u)
    partials[(size_t)p*NOUT + u*256 + t] = acc[u];   // coalesced across t
}

__global__ __launch_bounds__(256) void cell_kernel(const float* __restrict__ X,
                                                   const float* __restrict__ Y,
                                                   float* __restrict__ partials, int P){
  const int t = threadIdx.x;
  const int f = t & 127;
  const int h = t >> 7;             // wave-uniform
  if (h == 0) cell_body<0>(X, Y, partials, f, t, blockIdx.x, P);
  else        cell_body<1>(X, Y, partials, f, t, blockIdx.x, P);
}

__global__ __launch_bounds__(256) void reduce1_kernel(const float* __restrict__ partials,
                                                      float* __restrict__ partial2, int P){
  int o = (blockIdx.x % 68)*256 + threadIdx.x;   // 68*256 = NOUT exactly
  int c = blockIdx.x / 68;                       // 8 chunks
  int PC = (P + 7) >> 3;
  int p0 = c*PC, p1 = min(P, p0 + PC);
  float s0=0.f, s1=0.f, s2=0.f, s3=0.f;
  int p = p0;
  for (; p + 3 < p1; p += 4){
    s0 += partials[(size_t)(p+0)*NOUT + o];
    s1 += partials[(size_t)(p+1)*NOUT + o];
    s2 += partials[(size_t)(p+2)*NOUT + o];
    s3 += partials[(size_t)(p+3)*NOUT + o];
  }
  for (; p < p1; ++p) s0 += partials[(size_t)p*NOUT + o];
  partial2[(size_t)c*NOUT + o] = (s0+s1)+(s2+s3);
}

__global__ __launch_bounds__(256) void reduce2_kernel(const float* __restrict__ partial2,
                                                      float* __restrict__ G){
  int o = blockIdx.x*256 + threadIdx.x;          // grid 68
  float s = 0.f;
#pragma unroll
  for (int c = 0; c < 8; ++c) s += partial2[(size_t)c*NOUT + o];
  G[o] = s;
}

__device__ inline float getG(const float* __restrict__ G, int f, int i, int j){
  int a = i < j ? i : j, c = i < j ? j : i;
  int k = a*16 - (a*(a-1))/2 + (c - a);          // linear index of (a,c), a<=c
  int h = (k >= 68) ? 1 : 0;
  int u = k - h*68;
  return G[u*256 + h*128 + f];
}

__global__ __launch_bounds__(256) void final_kernel(const float* __restrict__ G,
                                                    const float* __restrict__ gene_part,
                                                    int ngp, float* __restrict__ out){
  int t = threadIdx.x;
  float v = 0.f;
  if (t < 128){
    int f = t;
    float d[16];
#pragma unroll
    for (int i = 0; i < 16; ++i) d[i] = getG(G, f, i, i);
    float sum = 0.f;
#pragma unroll
    for (int i = 0; i < 16; ++i){
#pragma unroll
      for (int j = 0; j < 16; ++j){
        float sqd = d[i] + d[j] - 2.f*getG(G, f, i, j);
        float dist = sqrtf(fmaxf(sqd, 0.f));
        sum += (((i < 8) == (j < 8)) ? -dist : dist);
      }
    }
    v = sum * (1.f/128.f) * (1.f/128.f);         // per-feature value / 128 features
  }
  float gp = 0.f;
  for (int idx = t; idx < ngp; idx += 256) gp += gene_part[idx];
  v += gp * (1.f/16384.f);                       // mean over clouds
  __shared__ float red[256];
  red[t] = v;
  __syncthreads();
  for (int s2 = 128; s2 > 0; s2 >>= 1){
    if (t < s2) red[t] += red[t + s2];
    __syncthreads();
  }
  if (t == 0) out[0] = red[0];
}

extern "C" void kernel_launch(void* const* d_in, const int* in_sizes, int n_in,
                              void* d_out, int out_size, void* d_ws, size_t ws_size,
                              hipStream_t stream){
  const float* X = (const float*)d_in[0];
  const float* Y = (const float*)d_in[1];
  float* out = (float*)d_out;

  float* wsf       = (float*)d_ws;
  float* gene_part = wsf;                        // 4096 floats
  float* Gbuf      = wsf + 4096;                 // NOUT floats
  float* partial2  = wsf + 4096 + NOUT;          // 8*NOUT floats
  float* partials  = wsf + 4096 + 9*NOUT;        // P*NOUT floats
  size_t head = 4096 + 9*(size_t)NOUT;
  size_t availf = (ws_size/4 > head) ? (ws_size/4 - head) : 0;
  int P = (int)(availf / NOUT);
  if (P > 256) P = 256;
  if (P < 1)  P = 1;

  gene_kernel<<<4096, 256, 0, stream>>>(X, Y, gene_part);
  cell_kernel<<<P, 256, 0, stream>>>(X, Y, partials, P);
  reduce1_kernel<<<68*8, 256, 0, stream>>>(partials, partial2, P);
  reduce2_kernel<<<68, 256, 0, stream>>>(partial2, Gbuf);
  final_kernel<<<1, 256, 0, stream>>>(Gbuf, gene_part, 4096, out);
}

// Round 3
// 138.343 us; speedup vs baseline: 1.2262x; 1.2262x over previous
//
#include <hip/hip_runtime.h>
#include <hip/hip_bf16.h>

#define B_CLOUDS 16384
#define NPAIR 136
#define NOUT 17408   // 136 pairs * 128 features = 68*256
#define NBLK 512     // fused grid: 2 blocks per CU

using frag8 = __attribute__((ext_vector_type(8))) short;
using f32x4 = __attribute__((ext_vector_type(4))) float;
using i32x4 = __attribute__((ext_vector_type(4))) int;

// Pack two f32 -> bf16x2 by truncation with ONE v_perm_b32.
__device__ inline int pack_bf16(float lo, float hi){
  unsigned a, b;
  __builtin_memcpy(&a, &hi, 4);
  __builtin_memcpy(&b, &lo, 4);
  return (int)__builtin_amdgcn_perm(a, b, 0x07060302u);
}

struct PairTab { int pi[NPAIR]; int pj[NPAIR]; };
constexpr PairTab make_pairs(){
  PairTab t{}; int u = 0;
  for (int i = 0; i < 16; ++i) for (int j = i; j < 16; ++j){ t.pi[u]=i; t.pj[u]=j; ++u; }
  return t;
}
constexpr PairTab PT = make_pairs();

// Accumulate 68 pair-products for feature f over the 4 clouds staged in cellbuf.
// cellbuf layout: [cloud 0..3][row 0..15][f 0..127] bf16, byte ^= ((row&7)<<4) swizzle.
template<int H>
__device__ inline void cell_accum(const int* cellbuf, int f, float (&cacc)[68]){
#pragma unroll
  for (int c = 0; c < 4; ++c){
    float z[16];
#pragma unroll
    for (int rr = 0; rr < 16; ++rr){
      int byte = (((c*16 + rr)*256) + f*2) ^ ((rr & 7) << 4);
      unsigned short v = *reinterpret_cast<const unsigned short*>(
          reinterpret_cast<const char*>(cellbuf) + byte);
      unsigned u32 = ((unsigned)v) << 16;
      float zz; __builtin_memcpy(&zz, &u32, 4);
      z[rr] = zz;
    }
#pragma unroll
    for (int u = 0; u < 68; ++u)    // compile-time indices -> all regs
      cacc[u] = fmaf(z[PT.pi[H*68+u]], z[PT.pj[H*68+u]], cacc[u]);
  }
}

// ---- fused: gene Gram via MFMA + cell Gram from the same loaded registers ----
__global__ __launch_bounds__(256, 2) void fused_kernel(const float* __restrict__ X,
                                                       const float* __restrict__ Y,
                                                       float* __restrict__ cell_partials,
                                                       float* __restrict__ gene_part){
  __shared__ int cellbuf[4096];        // 16 KB: 4 clouds x 16 rows x 128 f bf16 (swizzled)
  __shared__ float diag[4][16];
  __shared__ float gw[4];
  const int t = threadIdx.x;
  const int wave = t >> 6, lane = t & 63;
  const int r = lane & 15;             // row of Z (0-7 = X, 8-15 = Y)
  const int g = lane >> 4;             // k-group
  const int f = t & 127, h = t >> 7;   // cell assignment (h is wave-uniform)

  float cacc[68];
#pragma unroll
  for (int u = 0; u < 68; ++u) cacc[u] = 0.f;
  float gene_acc = 0.f;

  const int cbase = blockIdx.x * 32;   // 32 clouds per block, 8 passes of 4
  for (int pass = 0; pass < 8; ++pass){
    const int b = cbase + pass*4 + wave;
    const float* base = (r < 8) ? X + (size_t)b*4096 + (size_t)r*512
                                : Y + (size_t)b*4096 + (size_t)(r-8)*512;
    const float* p = base + g*8;
    f32x4 acc = {0.f,0.f,0.f,0.f};
#pragma unroll
    for (int kk = 0; kk < 16; ++kk){
      const float4* q4 = reinterpret_cast<const float4*>(p + kk*32);
      float4 v0 = q4[0];
      float4 v1 = q4[1];
      i32x4 fi;
      fi[0] = pack_bf16(v0.x, v0.y);
      fi[1] = pack_bf16(v0.z, v0.w);
      fi[2] = pack_bf16(v1.x, v1.y);
      fi[3] = pack_bf16(v1.z, v1.w);
      if (kk >= 12){                   // columns 384..511 -> stage for cell
        int byte = ((wave*16 + r)*256 + (kk-12)*64 + g*16) ^ ((r & 7) << 4);
        *reinterpret_cast<i32x4*>(reinterpret_cast<char*>(cellbuf) + byte) = fi;
      }
      frag8 fr = __builtin_bit_cast(frag8, fi);
      acc = __builtin_amdgcn_mfma_f32_16x16x32_bf16(fr, fr, acc, 0, 0, 0);
    }
    // C/D layout: col = lane&15, row = (lane>>4)*4 + q
    int qd = r - g*4;
    if (qd >= 0 && qd < 4) diag[wave][r] = acc[qd];
    __syncthreads();
    float s = 0.f;
#pragma unroll
    for (int q = 0; q < 4; ++q){
      int row = g*4 + q;
      float sqd = diag[wave][row] + diag[wave][r] - 2.f*acc[q];
      float dist = sqrtf(fmaxf(sqd, 0.f));
      s += (((row < 8) == (r < 8)) ? -dist : dist);
    }
    gene_acc += s;
    if (h == 0) cell_accum<0>(cellbuf, f, cacc);
    else        cell_accum<1>(cellbuf, f, cacc);
    __syncthreads();                   // protect cellbuf/diag before next pass
  }
  // gene reduction: wave shuffle + cross-wave LDS
#pragma unroll
  for (int off = 32; off > 0; off >>= 1) gene_acc += __shfl_xor(gene_acc, off);
  if (lane == 0) gw[wave] = gene_acc;
  __syncthreads();
  if (t == 0) gene_part[blockIdx.x] = (gw[0]+gw[1]+gw[2]+gw[3]) * (1.f/128.f);
  // cell partials (coalesced across t)
  float* dst = cell_partials + (size_t)blockIdx.x * NOUT;
#pragma unroll
  for (int u = 0; u < 68; ++u) dst[u*256 + t] = cacc[u];
}

__global__ __launch_bounds__(256) void reduce1_kernel(const float* __restrict__ partials,
                                                      float* __restrict__ partial2){
  int o = (blockIdx.x % 68)*256 + threadIdx.x;   // 68*256 = NOUT exactly
  int c = blockIdx.x / 68;                       // 8 chunks of 64 blocks
  int p0 = c*64, p1 = p0 + 64;
  float s0=0.f, s1=0.f, s2=0.f, s3=0.f;
  for (int p = p0; p < p1; p += 4){
    s0 += partials[(size_t)(p+0)*NOUT + o];
    s1 += partials[(size_t)(p+1)*NOUT + o];
    s2 += partials[(size_t)(p+2)*NOUT + o];
    s3 += partials[(size_t)(p+3)*NOUT + o];
  }
  partial2[(size_t)c*NOUT + o] = (s0+s1)+(s2+s3);
}

__device__ inline float getG(const float* __restrict__ G, int f, int i, int j){
  int a = i < j ? i : j, c = i < j ? j : i;
  int k = a*16 - (a*(a-1))/2 + (c - a);          // linear index of (a,c), a<=c
  int h = (k >= 68) ? 1 : 0;
  int u = k - h*68;
  return G[u*256 + h*128 + f];
}

__global__ __launch_bounds__(256) void reduce2_kernel(const float* __restrict__ partial2,
                                                      float* __restrict__ G){
  int o = blockIdx.x*256 + threadIdx.x;          // grid 68
  float s = 0.f;
#pragma unroll
  for (int c = 0; c < 8; ++c) s += partial2[(size_t)c*NOUT + o];
  G[o] = s;
}

__global__ __launch_bounds__(256) void final_kernel(const float* __restrict__ G,
                                                    const float* __restrict__ gene_part,
                                                    int ngp, float* __restrict__ out){
  int t = threadIdx.x;
  float v = 0.f;
  if (t < 128){
    int f = t;
    float d[16];
#pragma unroll
    for (int i = 0; i < 16; ++i) d[i] = getG(G, f, i, i);
    float sum = 0.f;
#pragma unroll
    for (int i = 0; i < 16; ++i){
#pragma unroll
      for (int j = 0; j < 16; ++j){
        float sqd = d[i] + d[j] - 2.f*getG(G, f, i, j);
        float dist = sqrtf(fmaxf(sqd, 0.f));
        sum += (((i < 8) == (j < 8)) ? -dist : dist);
      }
    }
    v = sum * (1.f/128.f) * (1.f/128.f);         // per-feature value / 128 features
  }
  float gp = 0.f;
  for (int idx = t; idx < ngp; idx += 256) gp += gene_part[idx];
  v += gp * (1.f/16384.f);                       // mean over clouds
  __shared__ float red[256];
  red[t] = v;
  __syncthreads();
  for (int s2 = 128; s2 > 0; s2 >>= 1){
    if (t < s2) red[t] += red[t + s2];
    __syncthreads();
  }
  if (t == 0) out[0] = red[0];
}

extern "C" void kernel_launch(void* const* d_in, const int* in_sizes, int n_in,
                              void* d_out, int out_size, void* d_ws, size_t ws_size,
                              hipStream_t stream){
  const float* X = (const float*)d_in[0];
  const float* Y = (const float*)d_in[1];
  float* out = (float*)d_out;

  float* wsf       = (float*)d_ws;
  float* gene_part = wsf;                        // NBLK floats
  float* Gbuf      = wsf + 1024;                 // NOUT floats
  float* partial2  = wsf + 1024 + NOUT;          // 8*NOUT floats
  float* partials  = wsf + 1024 + 9*NOUT;        // NBLK*NOUT floats (~35.6 MB)

  fused_kernel<<<NBLK, 256, 0, stream>>>(X, Y, partials, gene_part);
  reduce1_kernel<<<68*8, 256, 0, stream>>>(partials, partial2);
  reduce2_kernel<<<68, 256, 0, stream>>>(partial2, Gbuf);
  final_kernel<<<1, 256, 0, stream>>>(Gbuf, gene_part, NBLK, out);
}